// Round 1
// baseline (244.363 us; speedup 1.0000x reference)
//
#include <hip/hip_runtime.h>

typedef unsigned short u16;
typedef __bf16 bf16x8 __attribute__((ext_vector_type(8)));
typedef u16 u16x8 __attribute__((ext_vector_type(8)));
typedef float f32x4 __attribute__((ext_vector_type(4)));

static __device__ __forceinline__ u16 f2bf(float f) {
    union { float f; unsigned u; } x; x.f = f;
    unsigned r = x.u + 0x7fffu + ((x.u >> 16) & 1u);
    return (u16)(r >> 16);
}

static __device__ __forceinline__ void gl_lds16(const void* g, void* l) {
    __builtin_amdgcn_global_load_lds(
        (const __attribute__((address_space(1))) void*)g,
        (__attribute__((address_space(3))) void*)l, 16, 0, 0);
}

// ---------------- fp32 -> bf16 conversion (hidden states) ----------------
__global__ __launch_bounds__(256) void cvt_k(const float* __restrict__ src,
                                             u16* __restrict__ dst, int n) {
    int i = (blockIdx.x * 256 + threadIdx.x) * 4;
    if (i < n) {
        float4 v = *(const float4*)(src + i);
        ushort4 o;
        o.x = f2bf(v.x); o.y = f2bf(v.y); o.z = f2bf(v.z); o.w = f2bf(v.w);
        *(ushort4*)(dst + i) = o;
    }
}

// ---------------- weight transpose + cvt: W[K][N] fp32 -> WT[N][K] bf16 ----
__global__ __launch_bounds__(256) void transw_k(const float* __restrict__ w0,
                                                const float* __restrict__ w1,
                                                const float* __restrict__ w2,
                                                const float* __restrict__ w3,
                                                u16* __restrict__ wt) {
    __shared__ float T[64][65];
    const float* src = (blockIdx.z == 0) ? w0 : (blockIdx.z == 1) ? w1
                     : (blockIdx.z == 2) ? w2 : w3;
    u16* dst = wt + (size_t)blockIdx.z * 1048576;
    const int k0 = blockIdx.x * 64, n0 = blockIdx.y * 64;
    const int rr = threadIdx.x >> 6, col = threadIdx.x & 63;
#pragma unroll
    for (int i = 0; i < 16; ++i) {
        int row = i * 4 + rr;
        T[row][col] = src[(size_t)(k0 + row) * 1024 + n0 + col];
    }
    __syncthreads();
#pragma unroll
    for (int i = 0; i < 16; ++i) {
        int row = i * 4 + rr;
        dst[(size_t)(n0 + row) * 1024 + k0 + col] = f2bf(T[col][row]);
    }
}

// ---------------- bf16 GEMM: C[M,N] = A[M,1024] @ WT[N,1024]^T + bias ------
// mode 0: QKV fused (grid.y = 24, sel = y>>3), writes head-major bf16 [B,H,S,64]
// mode 1: O-proj   (grid.y = 8), writes fp32 row-major [M,1024]
__global__ __launch_bounds__(256, 2) void gemm_k(
    const u16* __restrict__ A, const u16* __restrict__ WT0,
    const float* __restrict__ b0, const float* __restrict__ b1,
    const float* __restrict__ b2,
    u16* __restrict__ o0, u16* __restrict__ o1, u16* __restrict__ o2,
    float* __restrict__ oF, int mode) {
    __shared__ alignas(16) u16 Al[128 * 32];
    __shared__ alignas(16) u16 Bl[128 * 32];

    const int tid = threadIdx.x;
    const int lane = tid & 63;
    const int wv = tid >> 6;
    const int wr = wv >> 1, wc = wv & 1;
    const int l15 = lane & 15, l4 = lane >> 4;

    const int mbase = blockIdx.x * 128;
    const int sel = blockIdx.y >> 3;
    const int nb = (blockIdx.y & 7) * 128;

    const u16* Ab = A + (size_t)mbase * 1024;
    const u16* Bb = WT0 + (size_t)sel * 1048576 + (size_t)nb * 1024;

    const int srow = tid >> 2;
    const int scol = (tid & 3) * 8;  // u16 units (16B per lane)

    f32x4 acc[4][4] = {};

    for (int k0 = 0; k0 < 1024; k0 += 32) {
        char* la = (char*)Al + wv * 1024;
        char* lb = (char*)Bl + wv * 1024;
        gl_lds16(Ab + (size_t)srow * 1024 + k0 + scol, la);
        gl_lds16(Ab + (size_t)(srow + 64) * 1024 + k0 + scol, la + 4096);
        gl_lds16(Bb + (size_t)srow * 1024 + k0 + scol, lb);
        gl_lds16(Bb + (size_t)(srow + 64) * 1024 + k0 + scol, lb + 4096);
        __syncthreads();

        bf16x8 af[4], bfr[4];
#pragma unroll
        for (int mr = 0; mr < 4; ++mr)
            af[mr] = *(const bf16x8*)(Al + (wr * 64 + mr * 16 + l15) * 32 + l4 * 8);
#pragma unroll
        for (int nr = 0; nr < 4; ++nr)
            bfr[nr] = *(const bf16x8*)(Bl + (wc * 64 + nr * 16 + l15) * 32 + l4 * 8);
#pragma unroll
        for (int mr = 0; mr < 4; ++mr)
#pragma unroll
            for (int nr = 0; nr < 4; ++nr)
                acc[mr][nr] = __builtin_amdgcn_mfma_f32_16x16x32_bf16(
                    af[mr], bfr[nr], acc[mr][nr], 0, 0, 0);
        __syncthreads();
    }

    const float* bias = (sel == 0) ? b0 : ((sel == 1) ? b1 : b2);
    u16* oH = (sel == 0) ? o0 : ((sel == 1) ? o1 : o2);
    const float scale = (mode == 0 && sel == 0) ? 0.125f : 1.0f;

#pragma unroll
    for (int mr = 0; mr < 4; ++mr)
#pragma unroll
        for (int nr = 0; nr < 4; ++nr) {
            int col = nb + wc * 64 + nr * 16 + l15;
            float bv_ = bias[col];
#pragma unroll
            for (int j = 0; j < 4; ++j) {
                int row = mbase + wr * 64 + mr * 16 + l4 * 4 + j;
                float v = (acc[mr][nr][j] + bv_) * scale;
                if (mode == 0) {
                    int b_ = row >> 12, s_ = row & 4095;
                    int h_ = col >> 6, d_ = col & 63;
                    oH[(((size_t)(b_ * 16 + h_) * 4096) + s_) * 64 + d_] = f2bf(v);
                } else {
                    oF[(size_t)row * 1024 + col] = v;
                }
            }
        }
}

// ---------------- sliding-window attention --------------------------------
// 1 block per (b,h,chunk); 8 waves x 32 q-rows; 12 kv-tiles of 64 keys.
__global__ __launch_bounds__(512, 2) void attn_k(
    const u16* __restrict__ Qh, const u16* __restrict__ Kh,
    const u16* __restrict__ Vh, const float* __restrict__ mask,
    u16* __restrict__ attnb) {
    __shared__ alignas(16) u16 Kl[64][72];
    __shared__ alignas(16) u16 Vt[64][72];
    __shared__ alignas(16) u16 Pl[8][32][72];
    __shared__ float maskl[64];

    const int tid = threadIdx.x;
    const int lane = tid & 63;
    const int wv = tid >> 6;
    const int blk = blockIdx.x;
    const int c = blk & 15;
    const int h = (blk >> 4) & 15;
    const int b = blk >> 8;

    const size_t bh = (size_t)(b * 16 + h) * 4096;
    const u16* Qb = Qh + bh * 64;
    const u16* Kb = Kh + bh * 64;
    const u16* Vb = Vh + bh * 64;

    const int l15 = lane & 15;
    const int l4 = lane >> 4;

    // Q fragments stay in registers for the whole kernel
    bf16x8 qf[2][2];
#pragma unroll
    for (int mr = 0; mr < 2; ++mr) {
        int qs = c * 256 + wv * 32 + mr * 16 + l15;
#pragma unroll
        for (int kk = 0; kk < 2; ++kk)
            qf[mr][kk] = *(const bf16x8*)(Qb + (size_t)qs * 64 + kk * 32 + l4 * 8);
    }

    f32x4 Ov[2][4] = {};
    float mrow[2][4], lrow[2][4];
#pragma unroll
    for (int mr = 0; mr < 2; ++mr)
#pragma unroll
        for (int j = 0; j < 4; ++j) { mrow[mr][j] = -INFINITY; lrow[mr][j] = 0.f; }

    const int key = tid >> 3;
    const int d0 = (tid & 7) * 8;

    for (int t = 0; t < 12; ++t) {
        __syncthreads();
        const int gk0 = c * 256 - 256 + t * 64;
        {
            int gk = gk0 + key;
            int gkc = min(max(gk, 0), 4095);
            u16x8 kv8 = *(const u16x8*)(Kb + (size_t)gkc * 64 + d0);
            *(u16x8*)(&Kl[key][d0]) = kv8;
            u16x8 vv8 = *(const u16x8*)(Vb + (size_t)gkc * 64 + d0);
#pragma unroll
            for (int e = 0; e < 8; ++e) Vt[d0 + e][key] = vv8[e];
            if (tid < 64) {
                int gm = gk0 + tid;
                maskl[tid] = (gm >= 0 && gm < 4096) ? mask[b * 4096 + gm] : 0.f;
            }
        }
        __syncthreads();

        // scores: S[32q x 64k] = Q @ K^T
        f32x4 sc[2][4] = {};
#pragma unroll
        for (int kk = 0; kk < 2; ++kk)
#pragma unroll
            for (int nr = 0; nr < 4; ++nr) {
                bf16x8 kf = *(const bf16x8*)(&Kl[nr * 16 + l15][kk * 32 + l4 * 8]);
                sc[0][nr] = __builtin_amdgcn_mfma_f32_16x16x32_bf16(qf[0][kk], kf, sc[0][nr], 0, 0, 0);
                sc[1][nr] = __builtin_amdgcn_mfma_f32_16x16x32_bf16(qf[1][kk], kf, sc[1][nr], 0, 0, 0);
            }

        // mask + online softmax (row group = 16 lanes sharing l>>4)
#pragma unroll
        for (int mr = 0; mr < 2; ++mr) {
#pragma unroll
            for (int j = 0; j < 4; ++j) {
                int qrow = c * 256 + wv * 32 + mr * 16 + l4 * 4 + j;
                float mx = -INFINITY;
#pragma unroll
                for (int nr = 0; nr < 4; ++nr) {
                    int gk = gk0 + nr * 16 + l15;
                    bool ok = (gk >= 0) && (gk < 4096) &&
                              (gk - qrow <= 256) && (qrow - gk <= 256);
                    float sv = ok ? (sc[mr][nr][j] + maskl[nr * 16 + l15]) : -1e9f;
                    sc[mr][nr][j] = sv;
                    mx = fmaxf(mx, sv);
                }
                mx = fmaxf(mx, __shfl_xor(mx, 1));
                mx = fmaxf(mx, __shfl_xor(mx, 2));
                mx = fmaxf(mx, __shfl_xor(mx, 4));
                mx = fmaxf(mx, __shfl_xor(mx, 8));
                float mnew = fmaxf(mrow[mr][j], mx);
                float alpha = __expf(mrow[mr][j] - mnew);
                mrow[mr][j] = mnew;
                float rs = 0.f;
#pragma unroll
                for (int nr = 0; nr < 4; ++nr) {
                    float p = __expf(sc[mr][nr][j] - mnew);
                    sc[mr][nr][j] = p;
                    rs += p;
                }
                rs += __shfl_xor(rs, 1);
                rs += __shfl_xor(rs, 2);
                rs += __shfl_xor(rs, 4);
                rs += __shfl_xor(rs, 8);
                lrow[mr][j] = lrow[mr][j] * alpha + rs;
#pragma unroll
                for (int nd = 0; nd < 4; ++nd) Ov[mr][nd][j] *= alpha;
            }
        }

        // P (C-layout) -> LDS -> A-layout fragments
#pragma unroll
        for (int mr = 0; mr < 2; ++mr)
#pragma unroll
            for (int nr = 0; nr < 4; ++nr)
#pragma unroll
                for (int j = 0; j < 4; ++j)
                    Pl[wv][mr * 16 + l4 * 4 + j][nr * 16 + l15] = f2bf(sc[mr][nr][j]);

        // O += P @ V
#pragma unroll
        for (int kk = 0; kk < 2; ++kk) {
            bf16x8 pf0 = *(const bf16x8*)(&Pl[wv][l15][kk * 32 + l4 * 8]);
            bf16x8 pf1 = *(const bf16x8*)(&Pl[wv][16 + l15][kk * 32 + l4 * 8]);
#pragma unroll
            for (int nd = 0; nd < 4; ++nd) {
                bf16x8 vf = *(const bf16x8*)(&Vt[nd * 16 + l15][kk * 32 + l4 * 8]);
                Ov[0][nd] = __builtin_amdgcn_mfma_f32_16x16x32_bf16(pf0, vf, Ov[0][nd], 0, 0, 0);
                Ov[1][nd] = __builtin_amdgcn_mfma_f32_16x16x32_bf16(pf1, vf, Ov[1][nd], 0, 0, 0);
            }
        }
    }

    // normalize + store, row-major [B*S, H*64] bf16
#pragma unroll
    for (int mr = 0; mr < 2; ++mr)
#pragma unroll
        for (int j = 0; j < 4; ++j) {
            float inv = 1.0f / lrow[mr][j];
            int qs = c * 256 + wv * 32 + mr * 16 + l4 * 4 + j;
            size_t rowb = ((size_t)b * 4096 + qs) * 1024;
#pragma unroll
            for (int nd = 0; nd < 4; ++nd)
                attnb[rowb + h * 64 + nd * 16 + l15] = f2bf(Ov[mr][nd][j] * inv);
        }
}

// ---------------------------------------------------------------------------
extern "C" void kernel_launch(void* const* d_in, const int* in_sizes, int n_in,
                              void* d_out, int out_size, void* d_ws, size_t ws_size,
                              hipStream_t stream) {
    (void)in_sizes; (void)n_in; (void)out_size; (void)ws_size;
    const float* hid  = (const float*)d_in[0];
    const float* mask = (const float*)d_in[1];
    const float* Wq = (const float*)d_in[2];
    const float* bq = (const float*)d_in[3];
    const float* Wk = (const float*)d_in[4];
    const float* bk = (const float*)d_in[5];
    const float* Wv = (const float*)d_in[6];
    const float* bv = (const float*)d_in[7];
    const float* Wo = (const float*)d_in[8];
    const float* bo = (const float*)d_in[9];
    float* out = (float*)d_out;

    char* ws = (char*)d_ws;
    u16* hidb  = (u16*)(ws);                       // 16 MB  [8192][1024] bf16
    u16* wt    = (u16*)(ws + (16u << 20));         // 8 MB   WT[4][1024][1024] bf16
    u16* Qh    = (u16*)(ws + (24u << 20));         // 16 MB  [B][H][S][64] bf16
    u16* Kh    = (u16*)(ws + (40u << 20));         // 16 MB
    u16* Vh    = (u16*)(ws + (56u << 20));         // 16 MB
    u16* attnb = (u16*)(ws + (72u << 20));         // 16 MB  [8192][1024] bf16

    cvt_k<<<dim3(8192), dim3(256), 0, stream>>>(hid, hidb, 8388608);
    transw_k<<<dim3(16, 16, 4), dim3(256), 0, stream>>>(Wq, Wk, Wv, Wo, wt);
    gemm_k<<<dim3(64, 24), dim3(256), 0, stream>>>(hidb, wt, bq, bk, bv,
                                                   Qh, Kh, Vh, (float*)nullptr, 0);
    attn_k<<<dim3(512), dim3(512), 0, stream>>>(Qh, Kh, Vh, mask, attnb);
    gemm_k<<<dim3(64, 8), dim3(256), 0, stream>>>(attnb, wt + 3 * 1048576, bo, bo, bo,
                                                  (u16*)nullptr, (u16*)nullptr, (u16*)nullptr,
                                                  out, 1);
}

// Round 2
// 188.166 us; speedup vs baseline: 1.2987x; 1.2987x over previous
//
#include <hip/hip_runtime.h>

typedef unsigned short u16;
typedef __bf16 bf16x8 __attribute__((ext_vector_type(8)));
typedef u16 u16x8 __attribute__((ext_vector_type(8)));
typedef float f32x4 __attribute__((ext_vector_type(4)));

#define LOG2E 1.4426950408889634f

static __device__ __forceinline__ u16 f2bf(float f) {
    union { float f; unsigned u; } x; x.f = f;
    unsigned r = x.u + 0x7fffu + ((x.u >> 16) & 1u);
    return (u16)(r >> 16);
}

static __device__ __forceinline__ void gl_lds16(const void* g, void* l) {
    __builtin_amdgcn_global_load_lds(
        (const __attribute__((address_space(1))) void*)g,
        (__attribute__((address_space(3))) void*)l, 16, 0, 0);
}

// ---------------- fp32 -> bf16 conversion (hidden states) ----------------
__global__ __launch_bounds__(256) void cvt_k(const float* __restrict__ src,
                                             u16* __restrict__ dst, int n) {
    int i = (blockIdx.x * 256 + threadIdx.x) * 4;
    if (i < n) {
        float4 v = *(const float4*)(src + i);
        ushort4 o;
        o.x = f2bf(v.x); o.y = f2bf(v.y); o.z = f2bf(v.z); o.w = f2bf(v.w);
        *(ushort4*)(dst + i) = o;
    }
}

// ---------------- weight transpose + cvt: W[K][N] fp32 -> WT[N][K] bf16 ----
__global__ __launch_bounds__(256) void transw_k(const float* __restrict__ w0,
                                                const float* __restrict__ w1,
                                                const float* __restrict__ w2,
                                                const float* __restrict__ w3,
                                                u16* __restrict__ wt) {
    __shared__ float T[64][65];
    const float* src = (blockIdx.z == 0) ? w0 : (blockIdx.z == 1) ? w1
                     : (blockIdx.z == 2) ? w2 : w3;
    u16* dst = wt + (size_t)blockIdx.z * 1048576;
    const int k0 = blockIdx.x * 64, n0 = blockIdx.y * 64;
    const int rr = threadIdx.x >> 6, col = threadIdx.x & 63;
#pragma unroll
    for (int i = 0; i < 16; ++i) {
        int row = i * 4 + rr;
        T[row][col] = src[(size_t)(k0 + row) * 1024 + n0 + col];
    }
    __syncthreads();
#pragma unroll
    for (int i = 0; i < 16; ++i) {
        int row = i * 4 + rr;
        dst[(size_t)(n0 + row) * 1024 + k0 + col] = f2bf(T[col][row]);
    }
}

// ---------------- bf16 GEMM: C[M,N] = A[M,1024] @ WT[N,1024]^T + bias ------
// mode 0: QKV fused (grid.y = 24, sel = y>>3), writes head-major bf16 [B,H,S,64]
//         Q is scaled by 0.125*log2(e)  (exp2-based softmax downstream)
// mode 1: O-proj   (grid.y = 8), writes fp32 row-major [M,1024]
__global__ __launch_bounds__(256, 2) void gemm_k(
    const u16* __restrict__ A, const u16* __restrict__ WT0,
    const float* __restrict__ b0, const float* __restrict__ b1,
    const float* __restrict__ b2,
    u16* __restrict__ o0, u16* __restrict__ o1, u16* __restrict__ o2,
    float* __restrict__ oF, int mode) {
    __shared__ alignas(16) u16 Al[128 * 32];
    __shared__ alignas(16) u16 Bl[128 * 32];

    const int tid = threadIdx.x;
    const int lane = tid & 63;
    const int wv = tid >> 6;
    const int wr = wv >> 1, wc = wv & 1;
    const int l15 = lane & 15, l4 = lane >> 4;

    const int mbase = blockIdx.x * 128;
    const int sel = blockIdx.y >> 3;
    const int nb = (blockIdx.y & 7) * 128;

    const u16* Ab = A + (size_t)mbase * 1024;
    const u16* Bb = WT0 + (size_t)sel * 1048576 + (size_t)nb * 1024;

    const int srow = tid >> 2;
    const int scol = (tid & 3) * 8;  // u16 units (16B per lane)

    f32x4 acc[4][4] = {};

    for (int k0 = 0; k0 < 1024; k0 += 32) {
        char* la = (char*)Al + wv * 1024;
        char* lb = (char*)Bl + wv * 1024;
        gl_lds16(Ab + (size_t)srow * 1024 + k0 + scol, la);
        gl_lds16(Ab + (size_t)(srow + 64) * 1024 + k0 + scol, la + 4096);
        gl_lds16(Bb + (size_t)srow * 1024 + k0 + scol, lb);
        gl_lds16(Bb + (size_t)(srow + 64) * 1024 + k0 + scol, lb + 4096);
        __syncthreads();

        bf16x8 af[4], bfr[4];
#pragma unroll
        for (int mr = 0; mr < 4; ++mr)
            af[mr] = *(const bf16x8*)(Al + (wr * 64 + mr * 16 + l15) * 32 + l4 * 8);
#pragma unroll
        for (int nr = 0; nr < 4; ++nr)
            bfr[nr] = *(const bf16x8*)(Bl + (wc * 64 + nr * 16 + l15) * 32 + l4 * 8);
#pragma unroll
        for (int mr = 0; mr < 4; ++mr)
#pragma unroll
            for (int nr = 0; nr < 4; ++nr)
                acc[mr][nr] = __builtin_amdgcn_mfma_f32_16x16x32_bf16(
                    af[mr], bfr[nr], acc[mr][nr], 0, 0, 0);
        __syncthreads();
    }

    const float* bias = (sel == 0) ? b0 : ((sel == 1) ? b1 : b2);
    u16* oH = (sel == 0) ? o0 : ((sel == 1) ? o1 : o2);
    const float scale = (mode == 0 && sel == 0) ? 0.125f * LOG2E : 1.0f;

#pragma unroll
    for (int mr = 0; mr < 4; ++mr)
#pragma unroll
        for (int nr = 0; nr < 4; ++nr) {
            int col = nb + wc * 64 + nr * 16 + l15;
            float bv_ = bias[col];
#pragma unroll
            for (int j = 0; j < 4; ++j) {
                int row = mbase + wr * 64 + mr * 16 + l4 * 4 + j;
                float v = (acc[mr][nr][j] + bv_) * scale;
                if (mode == 0) {
                    int b_ = row >> 12, s_ = row & 4095;
                    int h_ = col >> 6, d_ = col & 63;
                    oH[(((size_t)(b_ * 16 + h_) * 4096) + s_) * 64 + d_] = f2bf(v);
                } else {
                    oF[(size_t)row * 1024 + col] = v;
                }
            }
        }
}

// ---------------- sliding-window attention --------------------------------
// 1 block per (b,h,chunk); 8 waves x 32 q-rows; 12 kv-tiles of 64 keys.
// K staged via global_load_lds with XOR-swizzled source; V staged manually
// transposed with bank-balanced XOR swizzle; double-buffered, 1 barrier/tile.
// Wave-uniform tile max softmax (exact); per-wave band tile skipping.
__global__ __launch_bounds__(512, 2) void attn_k(
    const u16* __restrict__ Qh, const u16* __restrict__ Kh,
    const u16* __restrict__ Vh, const float* __restrict__ mask,
    u16* __restrict__ attnb) {
    __shared__ alignas(16) u16 Kt[2][4096];   // [key][64 d], key-row XOR swizzle
    __shared__ alignas(16) u16 Vt[2][4096];   // [d][64 key], key-block XOR swizzle
    __shared__ alignas(16) u16 Pl[8][16][72]; // per-wave P half (16 q rows)
    __shared__ float maskl[2][64];

    const int tid = threadIdx.x;
    const int lane = tid & 63;
    const int wv = tid >> 6;
    const int blk = blockIdx.x;
    const int c = blk & 15;
    const int h = (blk >> 4) & 15;
    const int b = blk >> 8;

    const size_t bh = (size_t)(b * 16 + h) * 4096;
    const u16* Qb = Qh + bh * 64;
    const u16* Kb = Kh + bh * 64;
    const u16* Vb = Vh + bh * 64;

    const int l15 = lane & 15;
    const int l4 = lane >> 4;
    const int qbase = c * 256 + wv * 32;

    // Q fragments stay in registers (already scaled by 0.125*log2e)
    bf16x8 qf[2][2];
#pragma unroll
    for (int mr = 0; mr < 2; ++mr) {
        int qs = qbase + mr * 16 + l15;
#pragma unroll
        for (int kk = 0; kk < 2; ++kk)
            qf[mr][kk] = *(const bf16x8*)(Qb + (size_t)qs * 64 + kk * 32 + l4 * 8);
    }

    f32x4 Ov[2][4] = {};
    float lpart[2][4] = {};
    float m = -3.0e38f;

    // staging index decomposition
    const int kkey = tid >> 3;          // K: row (key) 0..63
    const int kpos = tid & 7;           // K: 16B-block slot
    const int vd0 = (tid & 7) * 8;      // V: d block start
    const int vbx = (kkey >> 3) ^ (tid & 7); // V: (key>>3)^(d>>3)

    const int tmin = wv >> 1;
    const int tmax_t = (wv * 32 + 543) >> 6;

    // ---------------- prologue: stage tile 0 into buf 0 ----------------
    {
        const int gk0 = c * 256 - 256;
        int gkk = min(max(gk0 + kkey, 0), 4095);
        gl_lds16(Kb + (size_t)gkk * 64 + ((kpos ^ (kkey & 7)) * 8), &Kt[0][wv * 512]);
        u16x8 vv = *(const u16x8*)(Vb + (size_t)gkk * 64 + vd0);
#pragma unroll
        for (int e = 0; e < 8; ++e)
            Vt[0][(vd0 + e) * 64 + ((vbx ^ e) * 8) + (kkey & 7)] = vv[e];
        if (tid < 64) {
            int gm = gk0 + tid;
            maskl[0][tid] = (gm >= 0 && gm < 4096) ? mask[b * 4096 + gm] * LOG2E : -3.0e9f;
        }
    }
    __syncthreads();

    for (int t = 0; t < 12; ++t) {
        const int cur = t & 1, nxt = cur ^ 1;
        const int gk0 = c * 256 - 256 + t * 64;
        const bool pre = (t + 1 < 12);

        // issue next-tile loads early (global); LDS writes deferred past compute
        u16x8 vv = {};
        float mval = 0.f;
        if (pre) {
            const int gk0n = gk0 + 64;
            int gkk = min(max(gk0n + kkey, 0), 4095);
            gl_lds16(Kb + (size_t)gkk * 64 + ((kpos ^ (kkey & 7)) * 8), &Kt[nxt][wv * 512]);
            vv = *(const u16x8*)(Vb + (size_t)gkk * 64 + vd0);
            if (tid < 64) {
                int gm = gk0n + tid;
                mval = (gm >= 0 && gm < 4096) ? mask[b * 4096 + gm] * LOG2E : -3.0e9f;
            }
        }

        // ---------------- compute current tile (band waves only) --------
        if (t >= tmin && t <= tmax_t) {
            f32x4 sc[2][4] = {};
#pragma unroll
            for (int kk = 0; kk < 2; ++kk)
#pragma unroll
                for (int nr = 0; nr < 4; ++nr) {
                    int r = nr * 16 + l15;
                    bf16x8 kf = *(const bf16x8*)(&Kt[cur][r * 64 + (((kk * 4 + l4) ^ (r & 7)) * 8)]);
                    sc[0][nr] = __builtin_amdgcn_mfma_f32_16x16x32_bf16(qf[0][kk], kf, sc[0][nr], 0, 0, 0);
                    sc[1][nr] = __builtin_amdgcn_mfma_f32_16x16x32_bf16(qf[1][kk], kf, sc[1][nr], 0, 0, 0);
                }

            float amv[4]; int relb[4];
#pragma unroll
            for (int nr = 0; nr < 4; ++nr) {
                amv[nr] = maskl[cur][nr * 16 + l15];
                relb[nr] = gk0 + nr * 16 + l15 - qbase + 256;
            }

            float tmx = -3.0e9f;
#pragma unroll
            for (int mr = 0; mr < 2; ++mr)
#pragma unroll
                for (int nr = 0; nr < 4; ++nr)
#pragma unroll
                    for (int j = 0; j < 4; ++j) {
                        float sv = sc[mr][nr][j] + amv[nr];
                        unsigned u = (unsigned)(relb[nr] - (mr * 16 + l4 * 4 + j));
                        sv = (u <= 512u) ? sv : -3.0e9f;
                        sc[mr][nr][j] = sv;
                        tmx = fmaxf(tmx, sv);
                    }
            // wave-wide tile max (uniform)
            tmx = fmaxf(tmx, __shfl_xor(tmx, 1));
            tmx = fmaxf(tmx, __shfl_xor(tmx, 2));
            tmx = fmaxf(tmx, __shfl_xor(tmx, 4));
            tmx = fmaxf(tmx, __shfl_xor(tmx, 8));
            tmx = fmaxf(tmx, __shfl_xor(tmx, 16));
            tmx = fmaxf(tmx, __shfl_xor(tmx, 32));

            if (tmx > m) {  // wave-uniform branch
                float alpha = exp2f(m - tmx);
                m = tmx;
#pragma unroll
                for (int mr = 0; mr < 2; ++mr) {
#pragma unroll
                    for (int nd = 0; nd < 4; ++nd) Ov[mr][nd] *= alpha;
#pragma unroll
                    for (int j = 0; j < 4; ++j) lpart[mr][j] *= alpha;
                }
            }

#pragma unroll
            for (int mr = 0; mr < 2; ++mr)
#pragma unroll
                for (int j = 0; j < 4; ++j) {
                    float s0 = 0.f;
#pragma unroll
                    for (int nr = 0; nr < 4; ++nr) {
                        float p = exp2f(sc[mr][nr][j] - m);
                        sc[mr][nr][j] = p;
                        s0 += p;
                    }
                    lpart[mr][j] += s0;
                }

            // PV, one 16-q half at a time through per-wave LDS
#pragma unroll
            for (int mr = 0; mr < 2; ++mr) {
#pragma unroll
                for (int nr = 0; nr < 4; ++nr)
#pragma unroll
                    for (int j = 0; j < 4; ++j)
                        Pl[wv][l4 * 4 + j][nr * 16 + l15] = f2bf(sc[mr][nr][j]);
#pragma unroll
                for (int kk = 0; kk < 2; ++kk) {
                    bf16x8 pf = *(const bf16x8*)(&Pl[wv][l15][kk * 32 + l4 * 8]);
#pragma unroll
                    for (int nd = 0; nd < 4; ++nd) {
                        int r2 = nd * 16 + l15;
                        bf16x8 vf = *(const bf16x8*)(&Vt[cur][r2 * 64 +
                            (((kk * 4 + l4) ^ (r2 & 7) ^ ((r2 >> 3) & 7)) * 8)]);
                        Ov[mr][nd] = __builtin_amdgcn_mfma_f32_16x16x32_bf16(pf, vf, Ov[mr][nd], 0, 0, 0);
                    }
                }
            }
        }

        // deferred LDS writes for next tile
        if (pre) {
#pragma unroll
            for (int e = 0; e < 8; ++e)
                Vt[nxt][(vd0 + e) * 64 + ((vbx ^ e) * 8) + (kkey & 7)] = vv[e];
            if (tid < 64) maskl[nxt][tid] = mval;
        }
        __syncthreads();
    }

    // normalize + store, row-major [B*S, H*64] bf16
#pragma unroll
    for (int mr = 0; mr < 2; ++mr)
#pragma unroll
        for (int j = 0; j < 4; ++j) {
            float lr = lpart[mr][j];
            lr += __shfl_xor(lr, 1);
            lr += __shfl_xor(lr, 2);
            lr += __shfl_xor(lr, 4);
            lr += __shfl_xor(lr, 8);
            float inv = 1.0f / lr;
            int qs = qbase + mr * 16 + l4 * 4 + j;
            size_t rowb = ((size_t)b * 4096 + qs) * 1024;
#pragma unroll
            for (int nd = 0; nd < 4; ++nd)
                attnb[rowb + h * 64 + nd * 16 + l15] = f2bf(Ov[mr][nd][j] * inv);
        }
}

// ---------------------------------------------------------------------------
extern "C" void kernel_launch(void* const* d_in, const int* in_sizes, int n_in,
                              void* d_out, int out_size, void* d_ws, size_t ws_size,
                              hipStream_t stream) {
    (void)in_sizes; (void)n_in; (void)out_size; (void)ws_size;
    const float* hid  = (const float*)d_in[0];
    const float* mask = (const float*)d_in[1];
    const float* Wq = (const float*)d_in[2];
    const float* bq = (const float*)d_in[3];
    const float* Wk = (const float*)d_in[4];
    const float* bk = (const float*)d_in[5];
    const float* Wv = (const float*)d_in[6];
    const float* bv = (const float*)d_in[7];
    const float* Wo = (const float*)d_in[8];
    const float* bo = (const float*)d_in[9];
    float* out = (float*)d_out;

    char* ws = (char*)d_ws;
    u16* hidb  = (u16*)(ws);                       // 16 MB  [8192][1024] bf16
    u16* wt    = (u16*)(ws + (16u << 20));         // 8 MB   WT[4][1024][1024] bf16
    u16* Qh    = (u16*)(ws + (24u << 20));         // 16 MB  [B][H][S][64] bf16
    u16* Kh    = (u16*)(ws + (40u << 20));         // 16 MB
    u16* Vh    = (u16*)(ws + (56u << 20));         // 16 MB
    u16* attnb = (u16*)(ws + (72u << 20));         // 16 MB  [8192][1024] bf16

    cvt_k<<<dim3(8192), dim3(256), 0, stream>>>(hid, hidb, 8388608);
    transw_k<<<dim3(16, 16, 4), dim3(256), 0, stream>>>(Wq, Wk, Wv, Wo, wt);
    gemm_k<<<dim3(64, 24), dim3(256), 0, stream>>>(hidb, wt, bq, bk, bv,
                                                   Qh, Kh, Vh, (float*)nullptr, 0);
    attn_k<<<dim3(512), dim3(512), 0, stream>>>(Qh, Kh, Vh, mask, attnb);
    gemm_k<<<dim3(64, 8), dim3(256), 0, stream>>>(attnb, wt + 3 * 1048576, bo, bo, bo,
                                                  (u16*)nullptr, (u16*)nullptr, (u16*)nullptr,
                                                  out, 1);
}